// Round 15
// baseline (335.416 us; speedup 1.0000x reference)
//
#include <hip/hip_runtime.h>

// Output = jacobi(X, Mask1, 100) — the multigrid sweeps in the reference are
// dead code for the returned value (grids[0] is never mutated).
//
// Trapezoidal temporal blocking, register-resident (10 launches x TI=10,
// 128x64 tile, 512 threads, 4x4 cells/thread, 240 blocks = 1/CU).
//
// Halo exchanges by pipe:
//  - horizontal (lane±1): DPP wave shifts, zero LDS. lh = wave_shr:1 of my
//    right-col pack (lane i <- i-1 = left neighbor), rh = wave_shl:1 of my
//    left-col pack. old=0 AND bound_ctrl=true -> wave-end lanes get 0 under
//    either bound_ctrl convention. lane31<->32 crossings put bounded garbage
//    into tile-edge cells only (light-cone-tolerated; finite by convexity).
//  - vertical intra-wave (lane±32): permlane32_swap with the XOR identity
//    (r.x^r.y^own, interpretation-proof — proven r14).
//  - vertical cross-wave: ONE address-selected ds_read_b128 + ONE ds_write
//    per thread-iter into merged T/B strips S2[buf][T,B][10][32] (20.5 KB,
//    double-buffered, 1 barrier/iter, last iter skips publish+barrier).
// r14 measured DS ops ride the serial critical path (delta matched op-count
// arithmetic); this removes the L/R strips = the larger remaining DS share.
//
// Tile edges compute bounded garbage that never reaches the valid window
// (light-cone: HX=12 > TI-1, TI rows); exterior cells stay 0 via mask=0.

#define W 1024
#define H 1024
#define TILE_W 128
#define TILE_H 64
#define TI 10                    // fused iterations per launch
#define OS_X 104                 // valid cols per tile: [12, 116)
#define OS_Y 44                  // valid rows per tile: [10, 54)
#define HX 12                    // left col halo (>= TI, keeps 16B alignment)
#define NBX 10                   // 10*104 = 1040 >= 1024
#define NBY 24                   // 24*44  = 1056 >= 1024
#define NLAUNCH 10               // NLAUNCH * TI = 100

typedef unsigned uint2v __attribute__((ext_vector_type(2)));

__device__ __forceinline__ float4 ld4(const float* __restrict__ p, int gr, int gc) {
    // gc is a multiple of 4 and W%4==0 -> the quad is entirely in or out
    if ((unsigned)gr < (unsigned)H && (unsigned)gc < (unsigned)W)
        return *(const float4*)&p[gr * W + gc];
    return make_float4(0.f, 0.f, 0.f, 0.f);
}

__device__ __forceinline__ float4 rowstep(const float4 up, const float4 ce,
                                          const float4 dn, const float lf,
                                          const float rt, const float4 m) {
    float4 s, n;
    s.x = (up.x + dn.x) + (lf   + ce.y);
    s.y = (up.y + dn.y) + (ce.x + ce.z);
    s.z = (up.z + dn.z) + (ce.y + ce.w);
    s.w = (up.w + dn.w) + (ce.z + rt);
    n.x = fmaf(m.x, fmaf(0.25f, s.x, -ce.x), ce.x);
    n.y = fmaf(m.y, fmaf(0.25f, s.y, -ce.y), ce.y);
    n.z = fmaf(m.z, fmaf(0.25f, s.z, -ce.z), ce.z);
    n.w = fmaf(m.w, fmaf(0.25f, s.w, -ce.w), ce.w);
    return n;
}

// lane l <-> lane l^32 exchange of p, robust to permlane32_swap convention:
// r holds {own p, partner p} in SOME order per lane -> XOR recovers partner.
__device__ __forceinline__ float xchg32(float p) {
    unsigned u = __float_as_uint(p);
    uint2v r = __builtin_amdgcn_permlane32_swap(u, u, false, false);
    return __uint_as_float(r.x ^ r.y ^ u);
}

__device__ __forceinline__ float4 xchg32_4(const float4 p) {
    return make_float4(xchg32(p.x), xchg32(p.y), xchg32(p.z), xchg32(p.w));
}

// DPP wave shifts: 0x138 = WAVE_SHR1 (lane i <- lane i-1),
//                  0x130 = WAVE_SHL1 (lane i <- lane i+1).
// old = 0 and bound_ctrl = true -> invalid-source lanes read 0 either way.
__device__ __forceinline__ float dpp_from_lower(float v) {
    return __int_as_float(__builtin_amdgcn_update_dpp(
        0, __float_as_int(v), 0x138, 0xF, 0xF, true));
}
__device__ __forceinline__ float dpp_from_higher(float v) {
    return __int_as_float(__builtin_amdgcn_update_dpp(
        0, __float_as_int(v), 0x130, 0xF, 0xF, true));
}

__device__ __forceinline__ float4 sel4(bool c, const float4 a, const float4 b) {
    return make_float4(c ? a.x : b.x, c ? a.y : b.y,
                       c ? a.z : b.z, c ? a.w : b.w);
}

__global__ __launch_bounds__(512, 1) void jacobi_trap(
    const float* __restrict__ xin, const float* __restrict__ mask,
    float* __restrict__ xout)
{
    // [buf][0=top rows, 1=bottom rows][wave row + guard][pc]  (20.5 KB)
    __shared__ float4 S2[2][2][10][32];

    const int tid = threadIdx.x;
    const int pr  = tid >> 5;              // 0..15
    const int pc  = tid & 31;              // 0..31
    const int wid = tid >> 6;              // wave 0..7
    const bool lowHalf = (tid & 32) == 0;  // lanes<32 = upper patch (pr even)
    const int gx0 = (int)blockIdx.x * OS_X - HX;
    const int gy0 = (int)blockIdx.y * OS_Y - TI;
    const int gr0 = gy0 + pr * 4;
    const int gc0 = gx0 + pc * 4;          // multiple of 4

    // cells + mask -> registers first (global loads in flight early)
    float4 c[4], m[4];
    #pragma unroll
    for (int i = 0; i < 4; ++i) {
        c[i] = ld4(xin,  gr0 + i, gc0);
        m[i] = ld4(mask, gr0 + i, gc0);
    }

    // zero the T/B guard rows (wave 0's "above" and wave 7's "below"):
    // S2[b][0][9][j] and S2[b][1][0][j], b=0,1 -> 128 float4s.
    const float4 z4 = make_float4(0.f, 0.f, 0.f, 0.f);
    if (tid < 128) {
        int b = tid >> 6, rem = tid & 63;
        if (rem < 32) S2[b][0][9][rem] = z4;
        else          S2[b][1][0][rem - 32] = z4;
    }

    // initial publish into buffer 0: wave's top row (lowHalf c[0]) into T,
    // wave's bottom row (highHalf c[3]) into B — one address-selected write.
    {
        float4* dst = lowHalf ? &S2[0][0][wid + 1][pc] : &S2[0][1][wid + 1][pc];
        *dst = lowHalf ? c[0] : c[3];
    }
    __syncthreads();

    #pragma unroll 1
    for (int it = 0; it < TI; ++it) {
        const int rb = it & 1;

        // vertical intra-wave exchange (VALU): partner's boundary row
        const float4 p4 = sel4(lowHalf, c[3], c[0]);
        const float4 q4 = xchg32_4(p4);

        // vertical cross-wave: one address-selected ds_read_b128
        const float4* sp = lowHalf ? &S2[rb][1][wid][pc]       // above's bottom
                                   : &S2[rb][0][wid + 2][pc];  // below's top
        const float4 tb = *sp;
        const float4 th = sel4(lowHalf, tb, q4);
        const float4 bh = sel4(lowHalf, q4, tb);

        // horizontal halos via DPP wave shifts (no LDS)
        const float4 rcol = make_float4(c[0].w, c[1].w, c[2].w, c[3].w);
        const float4 lcol = make_float4(c[0].x, c[1].x, c[2].x, c[3].x);
        const float4 lh = make_float4(dpp_from_lower(rcol.x),  dpp_from_lower(rcol.y),
                                      dpp_from_lower(rcol.z),  dpp_from_lower(rcol.w));
        const float4 rh = make_float4(dpp_from_higher(lcol.x), dpp_from_higher(lcol.y),
                                      dpp_from_higher(lcol.z), dpp_from_higher(lcol.w));

        const float4 n0 = rowstep(th,   c[0], c[1], lh.x, rh.x, m[0]);
        const float4 n1 = rowstep(c[0], c[1], c[2], lh.y, rh.y, m[1]);
        const float4 n2 = rowstep(c[1], c[2], c[3], lh.z, rh.z, m[2]);
        const float4 n3 = rowstep(c[2], c[3], bh,   lh.w, rh.w, m[3]);
        c[0] = n0; c[1] = n1; c[2] = n2; c[3] = n3;

        if (it < TI - 1) {   // last iter: nobody reads these edges
            const int wb = rb ^ 1;
            float4* dst = lowHalf ? &S2[wb][0][wid + 1][pc]
                                  : &S2[wb][1][wid + 1][pc];
            *dst = lowHalf ? n0 : n3;
            __syncthreads();
        }
    }

    // store valid window: rows [TI, TILE_H-TI), cols [HX, HX+OS_X)
    const int lc = pc * 4;
    if (lc >= HX && lc < HX + OS_X && (unsigned)gc0 < (unsigned)W) {
        #pragma unroll
        for (int i = 0; i < 4; ++i) {
            int lr = pr * 4 + i;
            if (lr < TI || lr >= TILE_H - TI) continue;
            int gr = gy0 + lr;
            if ((unsigned)gr >= (unsigned)H) continue;
            *(float4*)&xout[gr * W + gc0] = c[i];
        }
    }
}

extern "C" void kernel_launch(void* const* d_in, const int* in_sizes, int n_in,
                              void* d_out, int out_size, void* d_ws, size_t ws_size,
                              hipStream_t stream) {
    const float* X = (const float*)d_in[0];   // (1,1,1024,1024)
    const float* M = (const float*)d_in[1];   // Mask1
    float* out = (float*)d_out;
    float* ws  = (float*)d_ws;                // 4 MB ping buffer

    dim3 grid(NBX, NBY), block(512);
    // l=0: X->ws; alternate; l=9 (odd) -> out. Valid-window union covers
    // the full domain, so ws/out are fully written before any read.
    const float* src = X;
    for (int l = 0; l < NLAUNCH; ++l) {
        float* dst = (l & 1) ? out : ws;
        jacobi_trap<<<grid, block, 0, stream>>>(src, M, dst);
        src = dst;
    }
}

// Round 16
// 110.603 us; speedup vs baseline: 3.0326x; 3.0326x over previous
//
#include <hip/hip_runtime.h>

// Output = jacobi(X, Mask1, 100) — the multigrid sweeps in the reference are
// dead code for the returned value (grids[0] is never mutated).
//
// Trapezoidal temporal blocking, register-resident (10 launches x TI=10,
// 128x64 tile, 512 threads, 4x4 cells/thread, 240 blocks = 1/CU).
//
// Halo exchanges by pipe:
//  - horizontal (lane±1): DPP wave shifts (VALU, no LDS) — proven correct in
//    r15 (wrong shifts would corrupt interior cols; absmax matched).
//  - vertical intra-wave (lane±32): permlane32_swap XOR identity (r14-proven).
//  - vertical cross-wave: merged T/B strips S2[buf][T,B][10][32] (20.5 KB).
//    r15 lesson: ternary-SELECTED LDS POINTERS in the hot loop caused a 3.3x
//    regression (generic-pointer path). Here: reads = TWO direct-indexed
//    ds_read_b128 + VALU value-select; writes = half-exec if/else direct
//    stores — exactly the r14-proven idioms. No pointer select anywhere.
//
// Tile edges compute bounded garbage that never reaches the valid window
// (light-cone: HX=12 > TI-1, TI rows); exterior cells stay 0 via mask=0.

#define W 1024
#define H 1024
#define TILE_W 128
#define TILE_H 64
#define TI 10                    // fused iterations per launch
#define OS_X 104                 // valid cols per tile: [12, 116)
#define OS_Y 44                  // valid rows per tile: [10, 54)
#define HX 12                    // left col halo (>= TI, keeps 16B alignment)
#define NBX 10                   // 10*104 = 1040 >= 1024
#define NBY 24                   // 24*44  = 1056 >= 1024
#define NLAUNCH 10               // NLAUNCH * TI = 100

typedef unsigned uint2v __attribute__((ext_vector_type(2)));

__device__ __forceinline__ float4 ld4(const float* __restrict__ p, int gr, int gc) {
    // gc is a multiple of 4 and W%4==0 -> the quad is entirely in or out
    if ((unsigned)gr < (unsigned)H && (unsigned)gc < (unsigned)W)
        return *(const float4*)&p[gr * W + gc];
    return make_float4(0.f, 0.f, 0.f, 0.f);
}

__device__ __forceinline__ float4 rowstep(const float4 up, const float4 ce,
                                          const float4 dn, const float lf,
                                          const float rt, const float4 m) {
    float4 s, n;
    s.x = (up.x + dn.x) + (lf   + ce.y);
    s.y = (up.y + dn.y) + (ce.x + ce.z);
    s.z = (up.z + dn.z) + (ce.y + ce.w);
    s.w = (up.w + dn.w) + (ce.z + rt);
    n.x = fmaf(m.x, fmaf(0.25f, s.x, -ce.x), ce.x);
    n.y = fmaf(m.y, fmaf(0.25f, s.y, -ce.y), ce.y);
    n.z = fmaf(m.z, fmaf(0.25f, s.z, -ce.z), ce.z);
    n.w = fmaf(m.w, fmaf(0.25f, s.w, -ce.w), ce.w);
    return n;
}

// lane l <-> lane l^32 exchange of p, robust to permlane32_swap convention:
// r holds {own p, partner p} in SOME order per lane -> XOR recovers partner.
__device__ __forceinline__ float xchg32(float p) {
    unsigned u = __float_as_uint(p);
    uint2v r = __builtin_amdgcn_permlane32_swap(u, u, false, false);
    return __uint_as_float(r.x ^ r.y ^ u);
}

__device__ __forceinline__ float4 xchg32_4(const float4 p) {
    return make_float4(xchg32(p.x), xchg32(p.y), xchg32(p.z), xchg32(p.w));
}

// DPP wave shifts: 0x138 = WAVE_SHR1 (lane i <- lane i-1),
//                  0x130 = WAVE_SHL1 (lane i <- lane i+1).
// old = 0 and bound_ctrl = true -> invalid-source lanes read 0 either way.
__device__ __forceinline__ float dpp_from_lower(float v) {
    return __int_as_float(__builtin_amdgcn_update_dpp(
        0, __float_as_int(v), 0x138, 0xF, 0xF, true));
}
__device__ __forceinline__ float dpp_from_higher(float v) {
    return __int_as_float(__builtin_amdgcn_update_dpp(
        0, __float_as_int(v), 0x130, 0xF, 0xF, true));
}

__device__ __forceinline__ float4 sel4(bool c, const float4 a, const float4 b) {
    return make_float4(c ? a.x : b.x, c ? a.y : b.y,
                       c ? a.z : b.z, c ? a.w : b.w);
}

__global__ __launch_bounds__(512, 1) void jacobi_trap(
    const float* __restrict__ xin, const float* __restrict__ mask,
    float* __restrict__ xout)
{
    // [buf][0=top rows, 1=bottom rows][wave row + guard][pc]  (20.5 KB)
    __shared__ float4 S2[2][2][10][32];

    const int tid = threadIdx.x;
    const int pr  = tid >> 5;              // 0..15
    const int pc  = tid & 31;              // 0..31
    const int wid = tid >> 6;              // wave 0..7
    const bool lowHalf = (tid & 32) == 0;  // lanes<32 = upper patch (pr even)
    const int gx0 = (int)blockIdx.x * OS_X - HX;
    const int gy0 = (int)blockIdx.y * OS_Y - TI;
    const int gr0 = gy0 + pr * 4;
    const int gc0 = gx0 + pc * 4;          // multiple of 4

    // cells + mask -> registers first (global loads in flight early)
    float4 c[4], m[4];
    #pragma unroll
    for (int i = 0; i < 4; ++i) {
        c[i] = ld4(xin,  gr0 + i, gc0);
        m[i] = ld4(mask, gr0 + i, gc0);
    }

    // zero the T/B guard rows: S2[b][0][9][j] (never-written top row 9) and
    // S2[b][1][0][j] (wave 0's "above"), b=0,1 -> 128 float4s.
    const float4 z4 = make_float4(0.f, 0.f, 0.f, 0.f);
    if (tid < 128) {
        int b = tid >> 6, rem = tid & 63;
        if (rem < 32) S2[b][0][9][rem] = z4;
        else          S2[b][1][0][rem - 32] = z4;
    }

    // initial publish into buffer 0 (half-exec if/else, direct indexing)
    if (lowHalf) S2[0][0][wid + 1][pc] = c[0];
    else         S2[0][1][wid + 1][pc] = c[3];
    __syncthreads();

    #pragma unroll 1
    for (int it = 0; it < TI; ++it) {
        const int rb = it & 1;

        // vertical intra-wave exchange (VALU): partner's boundary row
        const float4 p4 = sel4(lowHalf, c[3], c[0]);
        const float4 q4 = xchg32_4(p4);

        // vertical cross-wave: two direct-indexed ds_read_b128 (all lanes,
        // both in-bounds), then VALU select — no pointer select.
        const float4 tbA = S2[rb][1][wid    ][pc];   // above wave's bottom row
        const float4 tbB = S2[rb][0][wid + 2][pc];   // below wave's top row
        const float4 tb  = sel4(lowHalf, tbA, tbB);
        const float4 th  = sel4(lowHalf, tb, q4);
        const float4 bh  = sel4(lowHalf, q4, tb);

        // horizontal halos via DPP wave shifts (no LDS)
        const float4 rcol = make_float4(c[0].w, c[1].w, c[2].w, c[3].w);
        const float4 lcol = make_float4(c[0].x, c[1].x, c[2].x, c[3].x);
        const float4 lh = make_float4(dpp_from_lower(rcol.x),  dpp_from_lower(rcol.y),
                                      dpp_from_lower(rcol.z),  dpp_from_lower(rcol.w));
        const float4 rh = make_float4(dpp_from_higher(lcol.x), dpp_from_higher(lcol.y),
                                      dpp_from_higher(lcol.z), dpp_from_higher(lcol.w));

        const float4 n0 = rowstep(th,   c[0], c[1], lh.x, rh.x, m[0]);
        const float4 n1 = rowstep(c[0], c[1], c[2], lh.y, rh.y, m[1]);
        const float4 n2 = rowstep(c[1], c[2], c[3], lh.z, rh.z, m[2]);
        const float4 n3 = rowstep(c[2], c[3], bh,   lh.w, rh.w, m[3]);
        c[0] = n0; c[1] = n1; c[2] = n2; c[3] = n3;

        if (it < TI - 1) {   // last iter: nobody reads these edges
            const int wb = rb ^ 1;
            if (lowHalf) S2[wb][0][wid + 1][pc] = n0;
            else         S2[wb][1][wid + 1][pc] = n3;
            __syncthreads();
        }
    }

    // store valid window: rows [TI, TILE_H-TI), cols [HX, HX+OS_X)
    const int lc = pc * 4;
    if (lc >= HX && lc < HX + OS_X && (unsigned)gc0 < (unsigned)W) {
        #pragma unroll
        for (int i = 0; i < 4; ++i) {
            int lr = pr * 4 + i;
            if (lr < TI || lr >= TILE_H - TI) continue;
            int gr = gy0 + lr;
            if ((unsigned)gr >= (unsigned)H) continue;
            *(float4*)&xout[gr * W + gc0] = c[i];
        }
    }
}

extern "C" void kernel_launch(void* const* d_in, const int* in_sizes, int n_in,
                              void* d_out, int out_size, void* d_ws, size_t ws_size,
                              hipStream_t stream) {
    const float* X = (const float*)d_in[0];   // (1,1,1024,1024)
    const float* M = (const float*)d_in[1];   // Mask1
    float* out = (float*)d_out;
    float* ws  = (float*)d_ws;                // 4 MB ping buffer

    dim3 grid(NBX, NBY), block(512);
    // l=0: X->ws; alternate; l=9 (odd) -> out. Valid-window union covers
    // the full domain, so ws/out are fully written before any read.
    const float* src = X;
    for (int l = 0; l < NLAUNCH; ++l) {
        float* dst = (l & 1) ? out : ws;
        jacobi_trap<<<grid, block, 0, stream>>>(src, M, dst);
        src = dst;
    }
}

// Round 17
// 102.782 us; speedup vs baseline: 3.2634x; 1.0761x over previous
//
#include <hip/hip_runtime.h>

// Output = jacobi(X, Mask1, 100) — the multigrid sweeps in the reference are
// dead code for the returned value (grids[0] is never mutated).
//
// Trapezoidal temporal blocking, register-resident: 5 launches x TI=20.
// Tile 128x96, 512 threads, 6x4 cells/thread, OS 88x56 -> grid 12x19 = 228
// blocks <= 256 CUs (1 block/CU critical path — r11's 5x20 failed because it
// used 144 blocks; this keeps CU occupancy while halving launch count, which
// r16's cost model showed is the largest remaining slice: ~5 us fixed/launch).
//
// Halo exchange (r14-proven idioms only — direct LDS indexing, half-exec
// if/else, NO pointer selects [r15: 3.3x regression]; NO DPP [r16: VALU
// critical path]):
//  - horizontal: L/R col packs in LDS strips (b128 rows 0-3 + b64 rows 4-5)
//  - vertical intra-wave (lane^32): permlane32_swap XOR identity
//  - vertical cross-wave: half-exec T/B strips
// Double-buffered, 1 barrier/iter, last iter skips publish+barrier.
//
// Tile edges compute bounded garbage that never reaches the valid window
// (light-cone: valid cells are exactly TI=20 from every tile edge); exterior
// cells stay 0 via mask=0 + zero loads = the reference's zero padding.

#define W 1024
#define H 1024
#define TILE_W 128
#define TILE_H 96
#define TI 20                    // fused iterations per launch
#define OS_X 88                  // valid cols per tile: [20, 108)
#define OS_Y 56                  // valid rows per tile: [20, 76)
#define HX 20                    // left halo (= TI, multiple of 4)
#define NBX 12                   // 12*88 = 1056 >= 1024
#define NBY 19                   // 19*56 = 1064 >= 1024
#define NLAUNCH 5                // NLAUNCH * TI = 100

typedef unsigned uint2v __attribute__((ext_vector_type(2)));

__device__ __forceinline__ float4 ld4(const float* __restrict__ p, int gr, int gc) {
    // gc is a multiple of 4 and W%4==0 -> the quad is entirely in or out
    if ((unsigned)gr < (unsigned)H && (unsigned)gc < (unsigned)W)
        return *(const float4*)&p[gr * W + gc];
    return make_float4(0.f, 0.f, 0.f, 0.f);
}

__device__ __forceinline__ float4 rowstep(const float4 up, const float4 ce,
                                          const float4 dn, const float lf,
                                          const float rt, const float4 m) {
    float4 s, n;
    s.x = (up.x + dn.x) + (lf   + ce.y);
    s.y = (up.y + dn.y) + (ce.x + ce.z);
    s.z = (up.z + dn.z) + (ce.y + ce.w);
    s.w = (up.w + dn.w) + (ce.z + rt);
    n.x = fmaf(m.x, fmaf(0.25f, s.x, -ce.x), ce.x);
    n.y = fmaf(m.y, fmaf(0.25f, s.y, -ce.y), ce.y);
    n.z = fmaf(m.z, fmaf(0.25f, s.z, -ce.z), ce.z);
    n.w = fmaf(m.w, fmaf(0.25f, s.w, -ce.w), ce.w);
    return n;
}

// lane l <-> lane l^32 exchange, robust to permlane32_swap convention:
// r holds {own p, partner p} in SOME order per lane -> XOR recovers partner.
__device__ __forceinline__ float xchg32(float p) {
    unsigned u = __float_as_uint(p);
    uint2v r = __builtin_amdgcn_permlane32_swap(u, u, false, false);
    return __uint_as_float(r.x ^ r.y ^ u);
}

__device__ __forceinline__ float4 xchg32_4(const float4 p) {
    return make_float4(xchg32(p.x), xchg32(p.y), xchg32(p.z), xchg32(p.w));
}

__device__ __forceinline__ float4 sel4(bool c, const float4 a, const float4 b) {
    return make_float4(c ? a.x : b.x, c ? a.y : b.y,
                       c ? a.z : b.z, c ? a.w : b.w);
}

__global__ __launch_bounds__(512, 1) void jacobi_trap(
    const float* __restrict__ xin, const float* __restrict__ mask,
    float* __restrict__ xout)
{
    __shared__ float4 SL4[2][18][34];   // left-col rows 0-3  (+ guards)
    __shared__ float4 SR4[2][18][34];   // right-col rows 0-3
    __shared__ float2 SL2[2][18][34];   // left-col rows 4-5
    __shared__ float2 SR2[2][18][34];   // right-col rows 4-5
    __shared__ float4 STs[2][10][32];   // wave top rows   (+ row guard)
    __shared__ float4 SBs[2][10][32];   // wave bottom rows

    const int tid = threadIdx.x;
    const int pr  = tid >> 5;              // 0..15 (6 rows each)
    const int pc  = tid & 31;              // 0..31 (4 cols each)
    const int wid = tid >> 6;              // wave 0..7
    const bool lowHalf = (tid & 32) == 0;  // lanes<32 = upper patch (pr even)
    const int gx0 = (int)blockIdx.x * OS_X - HX;
    const int gy0 = (int)blockIdx.y * OS_Y - TI;
    const int gr0 = gy0 + pr * 6;
    const int gc0 = gx0 + pc * 4;          // multiple of 4

    // cells + mask -> registers first (global loads in flight early)
    float4 c[6], m[6];
    #pragma unroll
    for (int i = 0; i < 6; ++i) {
        c[i] = ld4(xin,  gr0 + i, gc0);
        m[i] = ld4(mask, gr0 + i, gc0);
    }

    // zero ONLY the read guards: SR* col 0, SL* col 33 (rows 0..17, both
    // bufs); STs row 9, SBs row 0 (cols 0..31, both bufs).
    const float4 z4 = make_float4(0.f, 0.f, 0.f, 0.f);
    const float2 z2 = make_float2(0.f, 0.f);
    if (tid < 72) {
        int b = tid / 36, r2 = tid % 36;
        if (r2 < 18) SR4[b][r2][0] = z4;
        else         SL4[b][r2 - 18][33] = z4;
    } else if (tid < 144) {
        int j = tid - 72, b = j / 36, r2 = j % 36;
        if (r2 < 18) SR2[b][r2][0] = z2;
        else         SL2[b][r2 - 18][33] = z2;
    } else if (tid < 272) {
        int j = tid - 144, b = j >> 6, rem = j & 63;
        if (rem < 32) STs[b][9][rem] = z4;
        else          SBs[b][0][rem - 32] = z4;
    }

    // initial publish into buffer 0 (disjoint from guards)
    SL4[0][pr + 1][pc + 1] = make_float4(c[0].x, c[1].x, c[2].x, c[3].x);
    SL2[0][pr + 1][pc + 1] = make_float2(c[4].x, c[5].x);
    SR4[0][pr + 1][pc + 1] = make_float4(c[0].w, c[1].w, c[2].w, c[3].w);
    SR2[0][pr + 1][pc + 1] = make_float2(c[4].w, c[5].w);
    if (lowHalf) STs[0][wid + 1][pc] = c[0];
    else         SBs[0][wid + 1][pc] = c[5];
    __syncthreads();

    #pragma unroll 1
    for (int it = 0; it < TI; ++it) {
        const int rb = it & 1;

        // vertical intra-wave exchange (VALU): partner's boundary row
        const float4 p4 = sel4(lowHalf, c[5], c[0]);
        const float4 q4 = xchg32_4(p4);

        // vertical cross-wave via half-exec strips (r14-proven pattern)
        float4 thL = z4, bhL = z4;
        if (lowHalf) thL = SBs[rb][wid][pc];          // wave above's bottom
        else         bhL = STs[rb][wid + 2][pc];      // wave below's top
        const float4 th = sel4(lowHalf, thL, q4);
        const float4 bh = sel4(lowHalf, q4, bhL);

        // horizontal via LDS strips, direct indexing
        const float4 lh4 = SR4[rb][pr + 1][pc];       // left's right col 0-3
        const float2 lh2 = SR2[rb][pr + 1][pc];       // left's right col 4-5
        const float4 rh4 = SL4[rb][pr + 1][pc + 2];   // right's left col 0-3
        const float2 rh2 = SL2[rb][pr + 1][pc + 2];   // right's left col 4-5

        const float4 n0 = rowstep(th,   c[0], c[1], lh4.x, rh4.x, m[0]);
        const float4 n1 = rowstep(c[0], c[1], c[2], lh4.y, rh4.y, m[1]);
        const float4 n2 = rowstep(c[1], c[2], c[3], lh4.z, rh4.z, m[2]);
        const float4 n3 = rowstep(c[2], c[3], c[4], lh4.w, rh4.w, m[3]);
        const float4 n4 = rowstep(c[3], c[4], c[5], lh2.x, rh2.x, m[4]);
        const float4 n5 = rowstep(c[4], c[5], bh,   lh2.y, rh2.y, m[5]);
        c[0] = n0; c[1] = n1; c[2] = n2; c[3] = n3; c[4] = n4; c[5] = n5;

        if (it < TI - 1) {   // last iter: nobody reads these edges
            const int wb = rb ^ 1;
            SL4[wb][pr + 1][pc + 1] = make_float4(n0.x, n1.x, n2.x, n3.x);
            SL2[wb][pr + 1][pc + 1] = make_float2(n4.x, n5.x);
            SR4[wb][pr + 1][pc + 1] = make_float4(n0.w, n1.w, n2.w, n3.w);
            SR2[wb][pr + 1][pc + 1] = make_float2(n4.w, n5.w);
            if (lowHalf) STs[wb][wid + 1][pc] = n0;
            else         SBs[wb][wid + 1][pc] = n5;
            __syncthreads();
        }
    }

    // store valid window: rows [TI, TILE_H-TI) = [20,76),
    // cols [HX, HX+OS_X) = [20,108)  -> pc in [5,26]
    if (pc >= 5 && pc <= 26 && (unsigned)gc0 < (unsigned)W) {
        #pragma unroll
        for (int i = 0; i < 6; ++i) {
            int lr = pr * 6 + i;
            if (lr < TI || lr >= TILE_H - TI) continue;
            int gr = gy0 + lr;
            if ((unsigned)gr >= (unsigned)H) continue;
            *(float4*)&xout[gr * W + gc0] = c[i];
        }
    }
}

extern "C" void kernel_launch(void* const* d_in, const int* in_sizes, int n_in,
                              void* d_out, int out_size, void* d_ws, size_t ws_size,
                              hipStream_t stream) {
    const float* X = (const float*)d_in[0];   // (1,1,1024,1024)
    const float* M = (const float*)d_in[1];   // Mask1
    float* out = (float*)d_out;
    float* ws  = (float*)d_ws;                // 4 MB ping buffer

    dim3 grid(NBX, NBY), block(512);
    // Parity chosen so the LAST launch writes d_out; every buffer's valid-
    // window union covers the full domain, so reads never see stale data.
    const float* src = X;
    for (int l = 0; l < NLAUNCH; ++l) {
        float* dst = ((NLAUNCH - 1 - l) & 1) ? ws : out;
        jacobi_trap<<<grid, block, 0, stream>>>(src, M, dst);
        src = dst;
    }
}

// Round 18
// 101.060 us; speedup vs baseline: 3.3190x; 1.0170x over previous
//
#include <hip/hip_runtime.h>

// Output = jacobi(X, Mask1, 100) — the multigrid sweeps in the reference are
// dead code for the returned value (grids[0] is never mutated).
//
// Trapezoidal temporal blocking, register-resident (r14 winner: 10 launches
// x TI=10, 128x64 tile, 512 threads, 4x4 cells/thread, 240 blocks = 1/CU).
// r18 micro-opts (no structural change):
//  - TI loop fully unrolled (templated PUB/rb) -> all LDS addresses become
//    base+immediate, ~12 VALU addr ops/iter removed (r14 forced unroll 1).
//  - masked-load merge: th/bh initialized to the permlane result, then a
//    half-exec LDS read overwrites only the active half -> 8 fewer cndmask.
// Halo scheme (proven r14): L/R col packs via LDS strips; vertical intra-wave
// via permlane32_swap XOR identity (interpretation-proof); vertical
// cross-wave via half-exec T/B strips. Double-buffered, 1 barrier/iter,
// last iter skips publish+barrier. No pointer selects (r15: 3.3x), no DPP
// (r16: +8us critical path).
//
// Tile edges compute bounded garbage that never reaches the valid window
// (light-cone: HX=12 > TI-1, TI rows); exterior cells stay 0 via mask=0.

#define W 1024
#define H 1024
#define TILE_W 128
#define TILE_H 64
#define TI 10                    // fused iterations per launch
#define OS_X 104                 // valid cols per tile: [12, 116)
#define OS_Y 44                  // valid rows per tile: [10, 54)
#define HX 12                    // left col halo (>= TI, keeps 16B alignment)
#define NBX 10                   // 10*104 = 1040 >= 1024
#define NBY 24                   // 24*44  = 1056 >= 1024
#define NLAUNCH 10               // NLAUNCH * TI = 100

typedef unsigned uint2v __attribute__((ext_vector_type(2)));

__device__ __forceinline__ float4 ld4(const float* __restrict__ p, int gr, int gc) {
    // gc is a multiple of 4 and W%4==0 -> the quad is entirely in or out
    if ((unsigned)gr < (unsigned)H && (unsigned)gc < (unsigned)W)
        return *(const float4*)&p[gr * W + gc];
    return make_float4(0.f, 0.f, 0.f, 0.f);
}

__device__ __forceinline__ float4 rowstep(const float4 up, const float4 ce,
                                          const float4 dn, const float lf,
                                          const float rt, const float4 m) {
    float4 s, n;
    s.x = (up.x + dn.x) + (lf   + ce.y);
    s.y = (up.y + dn.y) + (ce.x + ce.z);
    s.z = (up.z + dn.z) + (ce.y + ce.w);
    s.w = (up.w + dn.w) + (ce.z + rt);
    n.x = fmaf(m.x, fmaf(0.25f, s.x, -ce.x), ce.x);
    n.y = fmaf(m.y, fmaf(0.25f, s.y, -ce.y), ce.y);
    n.z = fmaf(m.z, fmaf(0.25f, s.z, -ce.z), ce.z);
    n.w = fmaf(m.w, fmaf(0.25f, s.w, -ce.w), ce.w);
    return n;
}

// lane l <-> lane l^32 exchange of p, robust to permlane32_swap convention:
// r holds {own p, partner p} in SOME order per lane -> XOR recovers partner.
__device__ __forceinline__ float xchg32(float p) {
    unsigned u = __float_as_uint(p);
    uint2v r = __builtin_amdgcn_permlane32_swap(u, u, false, false);
    return __uint_as_float(r.x ^ r.y ^ u);
}

__device__ __forceinline__ float4 xchg32_4(const float4 p) {
    return make_float4(xchg32(p.x), xchg32(p.y), xchg32(p.z), xchg32(p.w));
}

__device__ __forceinline__ float4 sel4(bool c, const float4 a, const float4 b) {
    return make_float4(c ? a.x : b.x, c ? a.y : b.y,
                       c ? a.z : b.z, c ? a.w : b.w);
}

__shared__ float4 SLs[2][18][34];   // left-col packs  (+ col guards)
__shared__ float4 SRs[2][18][34];   // right-col packs
__shared__ float4 STs[2][10][32];   // wave top rows   (+ row guard)
__shared__ float4 SBs[2][10][32];   // wave bottom rows

// One Jacobi iteration; RB and PUB are compile-time -> immediate LDS offsets.
template <int RB, bool PUB>
__device__ __forceinline__ void one_iter(
    int pr, int pc, int wid, bool lowHalf,
    float4 (&c)[4], const float4 (&m)[4])
{
    // vertical intra-wave exchange (VALU): partner's boundary row
    const float4 p4 = sel4(lowHalf, c[3], c[0]);
    const float4 q4 = xchg32_4(p4);

    // vertical cross-wave: half-exec masked loads MERGE into q4 copies
    float4 th = q4, bh = q4;
    if (lowHalf) th = SBs[RB][wid][pc];           // wave above's bottom row
    else         bh = STs[RB][wid + 2][pc];       // wave below's top row

    // horizontal via LDS strips, direct indexing
    const float4 lh = SRs[RB][pr + 1][pc];        // left's right col
    const float4 rh = SLs[RB][pr + 1][pc + 2];    // right's left col

    const float4 n0 = rowstep(th,   c[0], c[1], lh.x, rh.x, m[0]);
    const float4 n1 = rowstep(c[0], c[1], c[2], lh.y, rh.y, m[1]);
    const float4 n2 = rowstep(c[1], c[2], c[3], lh.z, rh.z, m[2]);
    const float4 n3 = rowstep(c[2], c[3], bh,   lh.w, rh.w, m[3]);
    c[0] = n0; c[1] = n1; c[2] = n2; c[3] = n3;

    if (PUB) {
        constexpr int WB = RB ^ 1;
        SLs[WB][pr + 1][pc + 1] = make_float4(n0.x, n1.x, n2.x, n3.x);
        SRs[WB][pr + 1][pc + 1] = make_float4(n0.w, n1.w, n2.w, n3.w);
        if (lowHalf) STs[WB][wid + 1][pc] = n0;
        else         SBs[WB][wid + 1][pc] = n3;
        __syncthreads();
    }
}

__global__ __launch_bounds__(512, 1) void jacobi_trap(
    const float* __restrict__ xin, const float* __restrict__ mask,
    float* __restrict__ xout)
{
    const int tid = threadIdx.x;
    const int pr  = tid >> 5;              // 0..15
    const int pc  = tid & 31;              // 0..31
    const int wid = tid >> 6;              // wave 0..7
    const bool lowHalf = (tid & 32) == 0;  // lanes<32 = upper patch (pr even)
    const int gx0 = (int)blockIdx.x * OS_X - HX;
    const int gy0 = (int)blockIdx.y * OS_Y - TI;
    const int gr0 = gy0 + pr * 4;
    const int gc0 = gx0 + pc * 4;          // multiple of 4

    // cells + mask -> registers first (global loads in flight early)
    float4 c[4], m[4];
    #pragma unroll
    for (int i = 0; i < 4; ++i) {
        c[i] = ld4(xin,  gr0 + i, gc0);
        m[i] = ld4(mask, gr0 + i, gc0);
    }

    // zero ONLY the read guards (deterministic, NaN-free halos):
    // SRs col 0, SLs col 33 (rows 0..17, both bufs); STs row 9, SBs row 0.
    const float4 z4 = make_float4(0.f, 0.f, 0.f, 0.f);
    if (tid < 72) {
        int b = tid / 36, r2 = tid % 36;
        if (r2 < 18) SRs[b][r2][0] = z4;
        else         SLs[b][r2 - 18][33] = z4;
    } else if (tid >= 128 && tid < 256) {
        int j = tid - 128, b = j >> 6, r3 = j & 63;
        if (r3 < 32) STs[b][9][r3] = z4;
        else         SBs[b][0][r3 - 32] = z4;
    }

    // publish initial edges into buffer 0 (disjoint from guard ring)
    SLs[0][pr + 1][pc + 1] = make_float4(c[0].x, c[1].x, c[2].x, c[3].x);
    SRs[0][pr + 1][pc + 1] = make_float4(c[0].w, c[1].w, c[2].w, c[3].w);
    if (lowHalf) STs[0][wid + 1][pc] = c[0];
    else         SBs[0][wid + 1][pc] = c[3];
    __syncthreads();

    // fully unrolled TI=10: rb = 0,1,0,1,... ; last iter skips publish
    one_iter<0, true >(pr, pc, wid, lowHalf, c, m);
    one_iter<1, true >(pr, pc, wid, lowHalf, c, m);
    one_iter<0, true >(pr, pc, wid, lowHalf, c, m);
    one_iter<1, true >(pr, pc, wid, lowHalf, c, m);
    one_iter<0, true >(pr, pc, wid, lowHalf, c, m);
    one_iter<1, true >(pr, pc, wid, lowHalf, c, m);
    one_iter<0, true >(pr, pc, wid, lowHalf, c, m);
    one_iter<1, true >(pr, pc, wid, lowHalf, c, m);
    one_iter<0, true >(pr, pc, wid, lowHalf, c, m);
    one_iter<1, false>(pr, pc, wid, lowHalf, c, m);

    // store valid window: rows [TI, TILE_H-TI), cols [HX, HX+OS_X)
    const int lc = pc * 4;
    if (lc >= HX && lc < HX + OS_X && (unsigned)gc0 < (unsigned)W) {
        #pragma unroll
        for (int i = 0; i < 4; ++i) {
            int lr = pr * 4 + i;
            if (lr < TI || lr >= TILE_H - TI) continue;
            int gr = gy0 + lr;
            if ((unsigned)gr >= (unsigned)H) continue;
            *(float4*)&xout[gr * W + gc0] = c[i];
        }
    }
}

extern "C" void kernel_launch(void* const* d_in, const int* in_sizes, int n_in,
                              void* d_out, int out_size, void* d_ws, size_t ws_size,
                              hipStream_t stream) {
    const float* X = (const float*)d_in[0];   // (1,1,1024,1024)
    const float* M = (const float*)d_in[1];   // Mask1
    float* out = (float*)d_out;
    float* ws  = (float*)d_ws;                // 4 MB ping buffer

    dim3 grid(NBX, NBY), block(512);
    // l=0: X->ws; alternate; l=9 (odd) -> out. Valid-window union covers
    // the full domain, so ws/out are fully written before any read.
    const float* src = X;
    for (int l = 0; l < NLAUNCH; ++l) {
        float* dst = (l & 1) ? out : ws;
        jacobi_trap<<<grid, block, 0, stream>>>(src, M, dst);
        src = dst;
    }
}